// Round 2
// baseline (823.493 us; speedup 1.0000x reference)
//
#include <hip/hip_runtime.h>

#define DIM 128
#define NSHARD 8

typedef __attribute__((ext_vector_type(2))) float f32x2;
typedef __attribute__((ext_vector_type(4))) _Float16 half4;
typedef __attribute__((ext_vector_type(8))) _Float16 half8;
typedef __attribute__((ext_vector_type(4))) float f32x4;

#define HP 136  // fp16 tile row stride (halfs): 128 + 8 pad (2-way = free)
#define UP 264  // fp16 tile row stride (halfs): 256 + 8 pad

__device__ __forceinline__ unsigned char to_fp8(float v) {
  return (unsigned char)(__builtin_amdgcn_cvt_pk_fp8_f32(v, v, 0, false) & 0xff);
}

// Capture-safe software grid barrier. Counter must be 0 at kernel start
// (zeroed by hipMemsetAsync each launch). Requires all blocks co-resident:
// every user kernel's grid is sized under its guaranteed occupancy capacity.
__device__ __forceinline__ void grid_bar(unsigned* ctr, unsigned target) {
  __syncthreads();
  if (threadIdx.x == 0) {
    __threadfence();  // release all my prior global writes to agent scope
    __hip_atomic_fetch_add(ctr, 1u, __ATOMIC_RELEASE, __HIP_MEMORY_SCOPE_AGENT);
    unsigned spin = 0;
    while (__hip_atomic_load(ctr, __ATOMIC_ACQUIRE, __HIP_MEMORY_SCOPE_AGENT) <
           target) {
      if (++spin > 20000000u) break;  // bail-out: fail absmax, never hang
      __builtin_amdgcn_s_sleep(1);
    }
    __threadfence();  // acquire: invalidate stale cached lines
  }
  __syncthreads();
}

// ---- fused CSR build + weight fp16 conversion (640 blocks, sw-barrier) ----
// Replaces conv_wall, hist_rank, scanA, scanB, scanC, scatter2 (6 launches -> 1).
__global__ __launch_bounds__(256, 4) void csr_coop(
    const float* __restrict__ Wk, const float* __restrict__ Wv,
    const float* __restrict__ Wo, const float* __restrict__ W1,
    const float* __restrict__ W2, _Float16* __restrict__ Wkh,
    _Float16* __restrict__ Wvh, _Float16* __restrict__ Woh,
    _Float16* __restrict__ W1h, _Float16* __restrict__ W2h,
    float* __restrict__ stats, const int* __restrict__ ei,
    int* __restrict__ cnt, int* __restrict__ rank, int* __restrict__ rs,
    int* __restrict__ rs_shard, int* __restrict__ esrc, int* __restrict__ bsum,
    unsigned* __restrict__ gb, int N, int E) {
  __shared__ int s[256];
  int t = threadIdx.x;
  int gtid = blockIdx.x * 256 + t;
  int nth = gridDim.x * 256;        // 640*256 = 163840
  unsigned nblk = gridDim.x;        // 640

  // P0: weight conversion + zero counters/stats
  if (gtid < 16384) Wkh[gtid] = (_Float16)Wk[gtid];
  else if (gtid < 32768) Wvh[gtid - 16384] = (_Float16)Wv[gtid - 16384];
  else if (gtid < 49152) Woh[gtid - 32768] = (_Float16)Wo[gtid - 32768];
  else if (gtid < 81920) W1h[gtid - 49152] = (_Float16)W1[gtid - 49152];
  else if (gtid < 114688) W2h[gtid - 81920] = (_Float16)W2[gtid - 81920];
  for (int j = gtid; j < N * NSHARD; j += nth) cnt[j] = 0;
  if (gtid < 512) stats[gtid] = 0.f;
  grid_bar(&gb[0], nblk);

  // P1: histogram with rank capture (sharded x8 to cut atomic contention)
  for (int e = gtid; e < E; e += nth)
    rank[e] = atomicAdd(&cnt[(e & (NSHARD - 1)) * N + ei[E + e]], 1);
  grid_bar(&gb[1], nblk);

  // P2: per-256-chunk scan (blocks 0..nblk2-1)
  int nblk2 = (N + 255) >> 8;  // 157
  if ((int)blockIdx.x < nblk2) {
    int i = blockIdx.x * 256 + t;
    int v = 0;
    if (i < N)
#pragma unroll
      for (int sh = 0; sh < NSHARD; sh++) v += cnt[sh * N + i];
    s[t] = v;
    __syncthreads();
    for (int off = 1; off < 256; off <<= 1) {
      int add = (t >= off) ? s[t - off] : 0;
      __syncthreads();
      s[t] += add;
      __syncthreads();
    }
    if (i < N) rs[i] = s[t] - v;
    if (t == 255) bsum[blockIdx.x] = s[t];
  }
  grid_bar(&gb[2], nblk);

  // P3: chunk-sum scan (block 0 only)
  if (blockIdx.x == 0) {
    int v = (t < nblk2) ? bsum[t] : 0;
    s[t] = v;
    __syncthreads();
    for (int off = 1; off < 256; off <<= 1) {
      int add = (t >= off) ? s[t - off] : 0;
      __syncthreads();
      s[t] += add;
      __syncthreads();
    }
    if (t < nblk2) bsum[t] = s[t] - v;
  }
  grid_bar(&gb[3], nblk);

  // P4: finalize row starts + per-shard bases
  if ((int)blockIdx.x < nblk2) {
    int i = blockIdx.x * 256 + t;
    if (i < N) {
      int b = rs[i] + bsum[blockIdx.x];
      rs[i] = b;
#pragma unroll
      for (int sh = 0; sh < NSHARD; sh++) {
        rs_shard[sh * N + i] = b;
        b += cnt[sh * N + i];
      }
    }
    if (i == 0) rs[N] = E;
  }
  grid_bar(&gb[4], nblk);

  // P5: atomic-free scatter
  for (int e = gtid; e < E; e += nth)
    esrc[rs_shard[(e & (NSHARD - 1)) * N + ei[E + e]] + rank[e]] = ei[e];
}

// ------------- KV projection via MFMA, interleaved fp8 KV output -------------
__global__ __launch_bounds__(256) void kv_mfma(const float* __restrict__ x,
    const _Float16* __restrict__ Wkh, const float* __restrict__ bk,
    const _Float16* __restrict__ Wvh, const float* __restrict__ bv,
    unsigned char* __restrict__ KV8, int N) {
  __shared__ _Float16 xs[64 * HP];  // 17.4 KB
  int tid = threadIdx.x;
  int base = blockIdx.x * 64;
  int lane = tid & 63, w = tid >> 6;
  int l15 = lane & 15, quad = lane >> 4;

  for (int i = tid; i < 64 * 32; i += 256) {
    int m = i >> 5, c4 = i & 31;
    float4 tv = ((const float4*)x)[(size_t)(base + m) * 32 + c4];
    half4 hv;
    hv.x = (_Float16)tv.x; hv.y = (_Float16)tv.y;
    hv.z = (_Float16)tv.z; hv.w = (_Float16)tv.w;
    *(half4*)&xs[m * HP + c4 * 4] = hv;
  }
  __syncthreads();

  half8 afr[4][4];
#pragma unroll
  for (int mt = 0; mt < 4; mt++)
#pragma unroll
    for (int ks = 0; ks < 4; ks++)
      afr[mt][ks] = *(const half8*)&xs[(mt * 16 + l15) * HP + ks * 32 + quad * 8];

  const _Float16* W = (w < 2) ? Wkh : Wvh;
  const float* bias = (w < 2) ? bk : bv;
  int voff = (w < 2) ? 0 : 4;
  int c0 = (w & 1) * 64;

#pragma unroll
  for (int nt = 0; nt < 4; nt++) {
    int f = c0 + nt * 16 + l15;
    half8 bfr[4];
#pragma unroll
    for (int ks = 0; ks < 4; ks++)
      bfr[ks] = *(const half8*)&W[(size_t)f * 128 + ks * 32 + quad * 8];
    f32x4 acc[4];
#pragma unroll
    for (int mt = 0; mt < 4; mt++) acc[mt] = (f32x4){0.f, 0.f, 0.f, 0.f};
#pragma unroll
    for (int ks = 0; ks < 4; ks++)
#pragma unroll
      for (int mt = 0; mt < 4; mt++)
        acc[mt] = __builtin_amdgcn_mfma_f32_16x16x32_f16(afr[mt][ks], bfr[ks],
                                                          acc[mt], 0, 0, 0);
    float bb = bias[f];
    int fo = (f >> 2) * 8 + (f & 3) + voff;  // interleaved byte offset
#pragma unroll
    for (int mt = 0; mt < 4; mt++)
#pragma unroll
      for (int r = 0; r < 4; r++)
        KV8[(size_t)(base + mt * 16 + quad * 4 + r) * 256 + fo] =
            to_fp8(acc[mt][r] + bb);
  }
}

// ---------------- fused attention aggregate: one wave per dst node ----------
__global__ __launch_bounds__(256) void attn_agg(const unsigned char* __restrict__ KV8,
    const float* __restrict__ x, const int* __restrict__ rs,
    const int* __restrict__ esrc, _Float16* __restrict__ attn16, int N) {
  int wave = threadIdx.x >> 6, lane = threadIdx.x & 63;
  int n = blockIdx.x * 4 + wave;
  if (n >= N) return;
  int l = lane & 31, s = lane >> 5;
  float4 q = *(const float4*)&x[(size_t)n * DIM + 4 * l];
  int beg = rs[n], end = rs[n + 1];
  float a0 = 0.f, a1 = 0.f, a2 = 0.f, a3 = 0.f, dloc = 0.f;
  for (int e = beg + s; e < end; e += 8) {
    bool hh[4];
    int ss[4];
#pragma unroll
    for (int u = 0; u < 4; u++) hh[u] = (e + 2 * u) < end;
    ss[0] = esrc[e];
#pragma unroll
    for (int u = 1; u < 4; u++) ss[u] = hh[u] ? esrc[e + 2 * u] : ss[0];
    uint2 kv[4];
#pragma unroll
    for (int u = 0; u < 4; u++)
      kv[u] = *(const uint2*)&KV8[(size_t)ss[u] * 256 + 8 * l];
    float p[4];
#pragma unroll
    for (int u = 0; u < 4; u++) {
      f32x2 k01 = __builtin_amdgcn_cvt_pk_f32_fp8(kv[u].x, false);
      f32x2 k23 = __builtin_amdgcn_cvt_pk_f32_fp8(kv[u].x, true);
      p[u] = k01[0] * q.x + k01[1] * q.y + k23[0] * q.z + k23[1] * q.w;
    }
#pragma unroll
    for (int u = 0; u < 4; u++) p[u] += __shfl_xor(p[u], 1);
#pragma unroll
    for (int u = 0; u < 4; u++) p[u] += __shfl_xor(p[u], 2);
#pragma unroll
    for (int u = 0; u < 4; u++) {
      float ev = hh[u] ? __expf(p[u] * 0.25f) : 0.f;
      dloc += ev;
      f32x2 v01 = __builtin_amdgcn_cvt_pk_f32_fp8(kv[u].y, false);
      f32x2 v23 = __builtin_amdgcn_cvt_pk_f32_fp8(kv[u].y, true);
      a0 += ev * v01[0];
      a1 += ev * v01[1];
      a2 += ev * v23[0];
      a3 += ev * v23[1];
    }
  }
  dloc += __shfl_xor(dloc, 32);
  a0 += __shfl_xor(a0, 32);
  a1 += __shfl_xor(a1, 32);
  a2 += __shfl_xor(a2, 32);
  a3 += __shfl_xor(a3, 32);
  if (s == 0) {
    float inv = 1.0f / (dloc + 1e-16f);
    half4 o;
    o.x = (_Float16)(a0 * inv);
    o.y = (_Float16)(a1 * inv);
    o.z = (_Float16)(a2 * inv);
    o.w = (_Float16)(a3 * inv);
    *(half4*)&attn16[(size_t)n * DIM + 4 * l] = o;
  }
}

// ------ O-projection + residual + BN1 stats + (grid barrier) + BN1 apply ----
// t never round-trips fp32: held fp16 in LDS, exits as BN1-applied h16.
// 625 blocks @ 3/CU capacity 768: all co-resident.
__global__ __launch_bounds__(256, 3) void o_proj_coop(
    const _Float16* __restrict__ attn16, const float* __restrict__ x,
    const _Float16* __restrict__ Woh, const float* __restrict__ bo,
    const float* __restrict__ g1, const float* __restrict__ bb1,
    _Float16* __restrict__ h16, float* __restrict__ stats,
    unsigned* __restrict__ gb, float invN, int N) {
  __shared__ _Float16 as16[64 * HP];  // 17.4 KB; attn frags, then t (fp16)
  __shared__ float cf[256];
  int tid = threadIdx.x;
  int base = blockIdx.x * 64;
  int lane = tid & 63, w = tid >> 6;
  int l15 = lane & 15, quad = lane >> 4;

  for (int i = tid; i < 64 * 16; i += 256) {
    int m = i >> 4, c8 = i & 15;
    *(half8*)&as16[m * HP + c8 * 8] =
        ((const half8*)attn16)[(size_t)(base + m) * 16 + c8];
  }
  __syncthreads();

  half8 afr[4][4];
#pragma unroll
  for (int mt = 0; mt < 4; mt++)
#pragma unroll
    for (int ks = 0; ks < 4; ks++)
      afr[mt][ks] = *(const half8*)&as16[(mt * 16 + l15) * HP + ks * 32 + quad * 8];
  __syncthreads();  // all waves done reading as16 before epilogue overwrites it

  int c0 = w * 32;
  f32x4 acc[4][2];
#pragma unroll
  for (int mt = 0; mt < 4; mt++)
#pragma unroll
    for (int nt = 0; nt < 2; nt++) acc[mt][nt] = (f32x4){0.f, 0.f, 0.f, 0.f};
#pragma unroll
  for (int ks = 0; ks < 4; ks++) {
    half8 b[2];
#pragma unroll
    for (int nt = 0; nt < 2; nt++)
      b[nt] = *(const half8*)&Woh[(size_t)(c0 + nt * 16 + l15) * 128 + ks * 32 +
                                  quad * 8];
#pragma unroll
    for (int mt = 0; mt < 4; mt++)
#pragma unroll
      for (int nt = 0; nt < 2; nt++)
        acc[mt][nt] =
            __builtin_amdgcn_mfma_f32_16x16x32_f16(afr[mt][ks], b[nt], acc[mt][nt], 0, 0, 0);
  }

#pragma unroll
  for (int nt = 0; nt < 2; nt++) {
    int f = c0 + nt * 16 + l15;
    float bb = bo[f];
    float s = 0.f, q = 0.f;
#pragma unroll
    for (int mt = 0; mt < 4; mt++) {
#pragma unroll
      for (int r = 0; r < 4; r++) {
        int row = mt * 16 + quad * 4 + r;
        float tv = acc[mt][nt][r] + bb + x[(size_t)(base + row) * DIM + f];
        as16[row * HP + f] = (_Float16)tv;  // stash t in LDS (disjoint (row,f))
        s += tv;
        q += tv * tv;
      }
    }
    s += __shfl_xor(s, 16);
    s += __shfl_xor(s, 32);
    q += __shfl_xor(q, 16);
    q += __shfl_xor(q, 32);
    if (quad == 0) {
      atomicAdd(&stats[f], s);
      atomicAdd(&stats[128 + f], q);
    }
  }

  grid_bar(gb, 625);  // stats1 complete everywhere

  if (tid < 128) {
    float mu = stats[tid] * invN;
    float var = stats[128 + tid] * invN - mu * mu;
    float a = rsqrtf(var + 1e-5f) * g1[tid];
    cf[tid] = a;
    cf[128 + tid] = bb1[tid] - mu * a;
  }
  __syncthreads();

  for (int i = tid; i < 64 * 16; i += 256) {
    int m = i >> 4, c8 = i & 15;
    half8 tv = *(const half8*)&as16[m * HP + c8 * 8];
    half8 hv;
#pragma unroll
    for (int j = 0; j < 8; j++) {
      int f = c8 * 8 + j;
      hv[j] = (_Float16)((float)tv[j] * cf[f] + cf[128 + f]);
    }
    ((half8*)h16)[(size_t)(base + m) * 16 + c8] = hv;
  }
}

// ---- fused FFN + BN2 stats + (grid barrier) + BN2 apply + final write ------
// z never touches HBM: stored fp16 in-place in hs across the barrier.
// LDS 51 KB -> 3 blocks/CU -> capacity 768 >= 625: all co-resident.
__global__ __launch_bounds__(256, 3) void ffn_coop(
    const _Float16* __restrict__ h16, const _Float16* __restrict__ W1h,
    const float* __restrict__ b1, const _Float16* __restrict__ W2h,
    const float* __restrict__ b2, const float* __restrict__ g2,
    const float* __restrict__ bb2, float* __restrict__ out,
    float* __restrict__ stats2, unsigned* __restrict__ gb, float invN, int N) {
  __shared__ _Float16 hs[64 * HP];  // 17.4 KB (h, then z fp16)
  __shared__ _Float16 us[64 * UP];  // 33.8 KB
  __shared__ float cf[256];
  int tid = threadIdx.x;
  int base = blockIdx.x * 64;
  int lane = tid & 63, w = tid >> 6;
  int l15 = lane & 15, quad = lane >> 4;

  for (int i = tid; i < 64 * 16; i += 256) {
    int m = i >> 4, c8 = i & 15;
    *(half8*)&hs[m * HP + c8 * 8] =
        ((const half8*)h16)[(size_t)(base + m) * 16 + c8];
  }
  __syncthreads();

  int n0 = w * 64;
  half8 afr[4][4];
#pragma unroll
  for (int mt = 0; mt < 4; mt++)
#pragma unroll
    for (int ks = 0; ks < 4; ks++)
      afr[mt][ks] = *(const half8*)&hs[(mt * 16 + l15) * HP + ks * 32 + quad * 8];

#pragma unroll
  for (int nt = 0; nt < 4; nt++) {
    int n = n0 + nt * 16 + l15;
    half8 bfr[4];
#pragma unroll
    for (int ks = 0; ks < 4; ks++)
      bfr[ks] = *(const half8*)&W1h[(size_t)n * 128 + ks * 32 + quad * 8];
    f32x4 acc[4];
#pragma unroll
    for (int mt = 0; mt < 4; mt++) acc[mt] = (f32x4){0.f, 0.f, 0.f, 0.f};
#pragma unroll
    for (int ks = 0; ks < 4; ks++)
#pragma unroll
      for (int mt = 0; mt < 4; mt++)
        acc[mt] = __builtin_amdgcn_mfma_f32_16x16x32_f16(afr[mt][ks], bfr[ks],
                                                          acc[mt], 0, 0, 0);
    float bias = b1[n];
#pragma unroll
    for (int mt = 0; mt < 4; mt++)
#pragma unroll
      for (int r = 0; r < 4; r++)
        us[(mt * 16 + quad * 4 + r) * UP + n] =
            (_Float16)fmaxf(acc[mt][r] + bias, 0.f);
  }
  __syncthreads();  // also orders all afr reads before hs epilogue writes

  int n2 = w * 32;
  f32x4 acc2[4][2];
#pragma unroll
  for (int mt = 0; mt < 4; mt++)
#pragma unroll
    for (int nt = 0; nt < 2; nt++) acc2[mt][nt] = (f32x4){0.f, 0.f, 0.f, 0.f};
  for (int ks = 0; ks < 8; ks++) {
    half8 a[4], b[2];
#pragma unroll
    for (int mt = 0; mt < 4; mt++)
      a[mt] = *(const half8*)&us[(mt * 16 + l15) * UP + ks * 32 + quad * 8];
#pragma unroll
    for (int nt = 0; nt < 2; nt++)
      b[nt] = *(const half8*)&W2h[(size_t)(n2 + nt * 16 + l15) * 256 + ks * 32 +
                                  quad * 8];
#pragma unroll
    for (int mt = 0; mt < 4; mt++)
#pragma unroll
      for (int nt = 0; nt < 2; nt++)
        acc2[mt][nt] =
            __builtin_amdgcn_mfma_f32_16x16x32_f16(a[mt], b[nt], acc2[mt][nt], 0, 0, 0);
  }

#pragma unroll
  for (int nt = 0; nt < 2; nt++) {
    int f = n2 + nt * 16 + l15;
    float bz = b2[f];
    float s = 0.f, q = 0.f;
#pragma unroll
    for (int mt = 0; mt < 4; mt++) {
#pragma unroll
      for (int r = 0; r < 4; r++) {
        int row = mt * 16 + quad * 4 + r;
        float hv = (float)hs[row * HP + f];
        float zv = hv + acc2[mt][nt][r] + bz;
        hs[row * HP + f] = (_Float16)zv;  // z in-place (disjoint (row,f))
        s += zv;
        q += zv * zv;
      }
    }
    s += __shfl_xor(s, 16);
    s += __shfl_xor(s, 32);
    q += __shfl_xor(q, 16);
    q += __shfl_xor(q, 32);
    if (quad == 0) {
      atomicAdd(&stats2[f], s);
      atomicAdd(&stats2[128 + f], q);
    }
  }

  grid_bar(gb, 625);  // stats2 complete everywhere

  if (tid < 128) {
    float mu = stats2[tid] * invN;
    float var = stats2[128 + tid] * invN - mu * mu;
    float a = rsqrtf(var + 1e-5f) * g2[tid];
    cf[tid] = a;
    cf[128 + tid] = bb2[tid] - mu * a;
  }
  __syncthreads();

  for (int i = tid; i < 64 * 16; i += 256) {
    int m = i >> 4, c8 = i & 15;
    half8 zv = *(const half8*)&hs[m * HP + c8 * 8];
    int f0 = c8 * 8;
    float4 o1, o2;
    o1.x = (float)zv[0] * cf[f0 + 0] + cf[128 + f0 + 0];
    o1.y = (float)zv[1] * cf[f0 + 1] + cf[128 + f0 + 1];
    o1.z = (float)zv[2] * cf[f0 + 2] + cf[128 + f0 + 2];
    o1.w = (float)zv[3] * cf[f0 + 3] + cf[128 + f0 + 3];
    o2.x = (float)zv[4] * cf[f0 + 4] + cf[128 + f0 + 4];
    o2.y = (float)zv[5] * cf[f0 + 5] + cf[128 + f0 + 5];
    o2.z = (float)zv[6] * cf[f0 + 6] + cf[128 + f0 + 6];
    o2.w = (float)zv[7] * cf[f0 + 7] + cf[128 + f0 + 7];
    size_t ob = (size_t)(base + m) * 32 + c8 * 2;
    ((float4*)out)[ob] = o1;
    ((float4*)out)[ob + 1] = o2;
  }
}

extern "C" void kernel_launch(void* const* d_in, const int* in_sizes, int n_in,
                              void* d_out, int out_size, void* d_ws, size_t ws_size,
                              hipStream_t stream) {
  const float* x = (const float*)d_in[0];
  const int* ei = (const int*)d_in[1];
  const float* Wk = (const float*)d_in[2];
  const float* bk = (const float*)d_in[3];
  const float* Wv = (const float*)d_in[4];
  const float* bv = (const float*)d_in[5];
  const float* Wo = (const float*)d_in[6];
  const float* bo = (const float*)d_in[7];
  const float* bn1_g = (const float*)d_in[8];
  const float* bn1_b = (const float*)d_in[9];
  const float* W1 = (const float*)d_in[10];
  const float* b1 = (const float*)d_in[11];
  const float* W2 = (const float*)d_in[12];
  const float* b2 = (const float*)d_in[13];
  const float* bn2_g = (const float*)d_in[14];
  const float* bn2_b = (const float*)d_in[15];
  float* out = (float*)d_out;

  int N = in_sizes[0] / DIM;   // 40000 (= 625 * 64)
  int E = in_sizes[1] / 2;     // 640000

  // workspace layout
  unsigned char* KV8 = (unsigned char*)d_ws;              // 10.25 MB
  _Float16* attn16 = (_Float16*)(KV8 + (size_t)N * 256);  // 10.25 MB
  _Float16* h16 = attn16 + (size_t)N * DIM;               // 10.25 MB
  _Float16* W1h = h16 + (size_t)N * DIM;
  _Float16* W2h = W1h + 32768;
  _Float16* Wkh = W2h + 32768;
  _Float16* Wvh = Wkh + 16384;
  _Float16* Woh = Wvh + 16384;
  float* stats = (float*)(Woh + 16384);      // 512 floats: stats1 | stats2
  int* cnt = (int*)(stats + 512);            // N * NSHARD
  int* rs = cnt + (size_t)N * NSHARD;        // N+1
  int* rs_shard = rs + N + 1;                // N * NSHARD
  int* rank = rs_shard + (size_t)N * NSHARD; // E
  int* esrc = rank + E;                      // E
  int* bsum = esrc + E;                      // 256
  unsigned* gb = (unsigned*)(bsum + 256);    // 8 barrier counters

  float invN = 1.0f / N;
  float* stats2 = stats + 256;
  int nwg = N / 64;  // 625

  hipMemsetAsync(gb, 0, 8 * sizeof(unsigned), stream);
  csr_coop<<<640, 256, 0, stream>>>(Wk, Wv, Wo, W1, W2, Wkh, Wvh, Woh, W1h,
                                    W2h, stats, ei, cnt, rank, rs, rs_shard,
                                    esrc, bsum, gb, N, E);
  kv_mfma<<<nwg, 256, 0, stream>>>(x, Wkh, bk, Wvh, bv, KV8, N);
  attn_agg<<<(N + 3) / 4, 256, 0, stream>>>(KV8, x, rs, esrc, attn16, N);
  o_proj_coop<<<nwg, 256, 0, stream>>>(attn16, x, Woh, bo, bn1_g, bn1_b, h16,
                                       stats, &gb[5], invN, N);
  ffn_coop<<<nwg, 256, 0, stream>>>(h16, W1h, b1, W2h, b2, bn2_g, bn2_b, out,
                                    stats2, &gb[6], invN, N);
}

// Round 3
// 240.170 us; speedup vs baseline: 3.4288x; 3.4288x over previous
//
#include <hip/hip_runtime.h>

#define DIM 128
#define NSHARD 8

typedef __attribute__((ext_vector_type(2))) float f32x2;
typedef __attribute__((ext_vector_type(4))) _Float16 half4;
typedef __attribute__((ext_vector_type(8))) _Float16 half8;
typedef __attribute__((ext_vector_type(4))) float f32x4;

#define HP 136  // fp16 tile row stride (halfs): 128 + 8 pad (2-way = free)
#define UP 264  // fp16 tile row stride (halfs): 256 + 8 pad

__device__ __forceinline__ unsigned char to_fp8(float v) {
  return (unsigned char)(__builtin_amdgcn_cvt_pk_fp8_f32(v, v, 0, false) & 0xff);
}

// ------- fp32 -> fp16 conversion of all weights + zero cnt/stats -------------
__global__ __launch_bounds__(256) void conv_wall(const float* __restrict__ Wk,
    const float* __restrict__ Wv, const float* __restrict__ Wo,
    const float* __restrict__ W1, const float* __restrict__ W2,
    _Float16* __restrict__ Wkh, _Float16* __restrict__ Wvh,
    _Float16* __restrict__ Woh, _Float16* __restrict__ W1h,
    _Float16* __restrict__ W2h, int* __restrict__ cnt, float* __restrict__ stats,
    int N) {
  int i = blockIdx.x * 256 + threadIdx.x;
  int nth = gridDim.x * 256;
  if (i < 16384) Wkh[i] = (_Float16)Wk[i];
  else if (i < 32768) Wvh[i - 16384] = (_Float16)Wv[i - 16384];
  else if (i < 49152) Woh[i - 32768] = (_Float16)Wo[i - 32768];
  else if (i < 81920) W1h[i - 49152] = (_Float16)W1[i - 49152];
  else if (i < 114688) W2h[i - 81920] = (_Float16)W2[i - 81920];
  for (int j = i; j < N * NSHARD; j += nth) cnt[j] = 0;
  if (i < 512) stats[i] = 0.f;
}

// ---------- CSR build: hist with rank capture, counters sharded x8 ----------
__global__ __launch_bounds__(256) void hist_rank(const int* __restrict__ ei,
    int* __restrict__ cnt, int* __restrict__ rank, int N, int E) {
  int e = blockIdx.x * 256 + threadIdx.x;
  if (e < E) rank[e] = atomicAdd(&cnt[(e & (NSHARD - 1)) * N + ei[E + e]], 1);
}

__global__ __launch_bounds__(256) void scanA(const int* __restrict__ cnt,
    int* __restrict__ rs, int* __restrict__ bsum, int N) {
  __shared__ int s[256];
  int t = threadIdx.x;
  int i = blockIdx.x * 256 + t;
  int v = 0;
  if (i < N)
#pragma unroll
    for (int sh = 0; sh < NSHARD; sh++) v += cnt[sh * N + i];
  s[t] = v;
  __syncthreads();
  for (int off = 1; off < 256; off <<= 1) {
    int add = (t >= off) ? s[t - off] : 0;
    __syncthreads();
    s[t] += add;
    __syncthreads();
  }
  if (i < N) rs[i] = s[t] - v;
  if (t == 255) bsum[blockIdx.x] = s[t];
}

// scanB folded in: every block re-scans the <=256 block sums in LDS (cheap),
// then finalizes row starts + per-shard bases. Kills the 1-block scanB launch.
__global__ __launch_bounds__(256) void scanBC(int* __restrict__ rs,
    const int* __restrict__ bsum, const int* __restrict__ cnt,
    int* __restrict__ rs_shard, int nblk, int N, int E) {
  __shared__ int s[256];
  __shared__ int ex[256];
  int t = threadIdx.x;
  int v = (t < nblk) ? bsum[t] : 0;
  s[t] = v;
  __syncthreads();
  for (int off = 1; off < 256; off <<= 1) {
    int add = (t >= off) ? s[t - off] : 0;
    __syncthreads();
    s[t] += add;
    __syncthreads();
  }
  ex[t] = s[t] - v;  // exclusive prefix of bsum
  __syncthreads();
  int boff = ex[blockIdx.x];
  int i = blockIdx.x * 256 + t;
  if (i < N) {
    int b = rs[i] + boff;
    rs[i] = b;
#pragma unroll
    for (int sh = 0; sh < NSHARD; sh++) {
      rs_shard[sh * N + i] = b;
      b += cnt[sh * N + i];
    }
  }
  if (i == 0) rs[N] = E;
}

// ------ merged: atomic-free scatter (blocks >= kvb) + KV projection ---------
// Independent stages: scatter needs scanBC, kv needs conv_wall; both feed
// attn_agg. Disjoint block ranges, uniform per-block branch.
__global__ __launch_bounds__(256) void scatter_kv(const int* __restrict__ ei,
    const int* __restrict__ rs_shard, const int* __restrict__ rank,
    int* __restrict__ esrc, const float* __restrict__ x,
    const _Float16* __restrict__ Wkh, const float* __restrict__ bk,
    const _Float16* __restrict__ Wvh, const float* __restrict__ bv,
    unsigned char* __restrict__ KV8, int kvb, int N, int E) {
  __shared__ _Float16 xs[64 * HP];  // 17.4 KB (kv blocks only)
  int tid = threadIdx.x;
  if ((int)blockIdx.x >= kvb) {
    int e = ((int)blockIdx.x - kvb) * 256 + tid;
    if (e < E)
      esrc[rs_shard[(e & (NSHARD - 1)) * N + ei[E + e]] + rank[e]] = ei[e];
    return;
  }
  int base = blockIdx.x * 64;
  int lane = tid & 63, w = tid >> 6;
  int l15 = lane & 15, quad = lane >> 4;

  for (int i = tid; i < 64 * 32; i += 256) {
    int m = i >> 5, c4 = i & 31;
    float4 tv = ((const float4*)x)[(size_t)(base + m) * 32 + c4];
    half4 hv;
    hv.x = (_Float16)tv.x; hv.y = (_Float16)tv.y;
    hv.z = (_Float16)tv.z; hv.w = (_Float16)tv.w;
    *(half4*)&xs[m * HP + c4 * 4] = hv;
  }
  __syncthreads();

  half8 afr[4][4];
#pragma unroll
  for (int mt = 0; mt < 4; mt++)
#pragma unroll
    for (int ks = 0; ks < 4; ks++)
      afr[mt][ks] = *(const half8*)&xs[(mt * 16 + l15) * HP + ks * 32 + quad * 8];

  const _Float16* W = (w < 2) ? Wkh : Wvh;
  const float* bias = (w < 2) ? bk : bv;
  int voff = (w < 2) ? 0 : 4;
  int c0 = (w & 1) * 64;

#pragma unroll
  for (int nt = 0; nt < 4; nt++) {
    int f = c0 + nt * 16 + l15;
    half8 bfr[4];
#pragma unroll
    for (int ks = 0; ks < 4; ks++)
      bfr[ks] = *(const half8*)&W[(size_t)f * 128 + ks * 32 + quad * 8];
    f32x4 acc[4];
#pragma unroll
    for (int mt = 0; mt < 4; mt++) acc[mt] = (f32x4){0.f, 0.f, 0.f, 0.f};
#pragma unroll
    for (int ks = 0; ks < 4; ks++)
#pragma unroll
      for (int mt = 0; mt < 4; mt++)
        acc[mt] = __builtin_amdgcn_mfma_f32_16x16x32_f16(afr[mt][ks], bfr[ks],
                                                          acc[mt], 0, 0, 0);
    float bb = bias[f];
    int fo = (f >> 2) * 8 + (f & 3) + voff;  // interleaved byte offset
#pragma unroll
    for (int mt = 0; mt < 4; mt++)
#pragma unroll
      for (int r = 0; r < 4; r++)
        KV8[(size_t)(base + mt * 16 + quad * 4 + r) * 256 + fo] =
            to_fp8(acc[mt][r] + bb);
  }
}

// ---------------- fused attention aggregate: one wave per dst node ----------
__global__ __launch_bounds__(256) void attn_agg(const unsigned char* __restrict__ KV8,
    const float* __restrict__ x, const int* __restrict__ rs,
    const int* __restrict__ esrc, _Float16* __restrict__ attn16, int N) {
  int wave = threadIdx.x >> 6, lane = threadIdx.x & 63;
  int n = blockIdx.x * 4 + wave;
  if (n >= N) return;
  int l = lane & 31, s = lane >> 5;
  float4 q = *(const float4*)&x[(size_t)n * DIM + 4 * l];
  int beg = rs[n], end = rs[n + 1];
  float a0 = 0.f, a1 = 0.f, a2 = 0.f, a3 = 0.f, dloc = 0.f;
  for (int e = beg + s; e < end; e += 8) {
    bool hh[4];
    int ss[4];
#pragma unroll
    for (int u = 0; u < 4; u++) hh[u] = (e + 2 * u) < end;
    ss[0] = esrc[e];
#pragma unroll
    for (int u = 1; u < 4; u++) ss[u] = hh[u] ? esrc[e + 2 * u] : ss[0];
    uint2 kv[4];
#pragma unroll
    for (int u = 0; u < 4; u++)
      kv[u] = *(const uint2*)&KV8[(size_t)ss[u] * 256 + 8 * l];
    float p[4];
#pragma unroll
    for (int u = 0; u < 4; u++) {
      f32x2 k01 = __builtin_amdgcn_cvt_pk_f32_fp8(kv[u].x, false);
      f32x2 k23 = __builtin_amdgcn_cvt_pk_f32_fp8(kv[u].x, true);
      p[u] = k01[0] * q.x + k01[1] * q.y + k23[0] * q.z + k23[1] * q.w;
    }
#pragma unroll
    for (int u = 0; u < 4; u++) p[u] += __shfl_xor(p[u], 1);
#pragma unroll
    for (int u = 0; u < 4; u++) p[u] += __shfl_xor(p[u], 2);
#pragma unroll
    for (int u = 0; u < 4; u++) {
      float ev = hh[u] ? __expf(p[u] * 0.25f) : 0.f;
      dloc += ev;
      f32x2 v01 = __builtin_amdgcn_cvt_pk_f32_fp8(kv[u].y, false);
      f32x2 v23 = __builtin_amdgcn_cvt_pk_f32_fp8(kv[u].y, true);
      a0 += ev * v01[0];
      a1 += ev * v01[1];
      a2 += ev * v23[0];
      a3 += ev * v23[1];
    }
  }
  dloc += __shfl_xor(dloc, 32);
  a0 += __shfl_xor(a0, 32);
  a1 += __shfl_xor(a1, 32);
  a2 += __shfl_xor(a2, 32);
  a3 += __shfl_xor(a3, 32);
  if (s == 0) {
    float inv = 1.0f / (dloc + 1e-16f);
    half4 o;
    o.x = (_Float16)(a0 * inv);
    o.y = (_Float16)(a1 * inv);
    o.z = (_Float16)(a2 * inv);
    o.w = (_Float16)(a3 * inv);
    *(half4*)&attn16[(size_t)n * DIM + 4 * l] = o;
  }
}

// ------- O-projection via MFMA + residual + BN1 stats; t stored fp16 --------
// Stats computed from fp32 register values; only the stored t is rounded
// (R2 proved absmax unchanged at 0.03125).
__global__ __launch_bounds__(256) void o_proj_mfma(const _Float16* __restrict__ attn16,
    const float* __restrict__ x, const _Float16* __restrict__ Woh,
    const float* __restrict__ bo, _Float16* __restrict__ t16,
    float* __restrict__ stats, int N) {
  __shared__ _Float16 as16[64 * HP];  // 17.4 KB
  int tid = threadIdx.x;
  int base = blockIdx.x * 64;
  int lane = tid & 63, w = tid >> 6;
  int l15 = lane & 15, quad = lane >> 4;

  for (int i = tid; i < 64 * 16; i += 256) {
    int m = i >> 4, c8 = i & 15;
    *(half8*)&as16[m * HP + c8 * 8] =
        ((const half8*)attn16)[(size_t)(base + m) * 16 + c8];
  }
  __syncthreads();

  half8 afr[4][4];
#pragma unroll
  for (int mt = 0; mt < 4; mt++)
#pragma unroll
    for (int ks = 0; ks < 4; ks++)
      afr[mt][ks] = *(const half8*)&as16[(mt * 16 + l15) * HP + ks * 32 + quad * 8];

  int c0 = w * 32;
  f32x4 acc[4][2];
#pragma unroll
  for (int mt = 0; mt < 4; mt++)
#pragma unroll
    for (int nt = 0; nt < 2; nt++) acc[mt][nt] = (f32x4){0.f, 0.f, 0.f, 0.f};
#pragma unroll
  for (int ks = 0; ks < 4; ks++) {
    half8 b[2];
#pragma unroll
    for (int nt = 0; nt < 2; nt++)
      b[nt] = *(const half8*)&Woh[(size_t)(c0 + nt * 16 + l15) * 128 + ks * 32 +
                                  quad * 8];
#pragma unroll
    for (int mt = 0; mt < 4; mt++)
#pragma unroll
      for (int nt = 0; nt < 2; nt++)
        acc[mt][nt] =
            __builtin_amdgcn_mfma_f32_16x16x32_f16(afr[mt][ks], b[nt], acc[mt][nt], 0, 0, 0);
  }

#pragma unroll
  for (int nt = 0; nt < 2; nt++) {
    int f = c0 + nt * 16 + l15;
    float bb = bo[f];
    float s = 0.f, q = 0.f;
#pragma unroll
    for (int mt = 0; mt < 4; mt++) {
#pragma unroll
      for (int r = 0; r < 4; r++) {
        int row = mt * 16 + quad * 4 + r;
        float tv = acc[mt][nt][r] + bb + x[(size_t)(base + row) * DIM + f];
        t16[(size_t)(base + row) * DIM + f] = (_Float16)tv;
        s += tv;
        q += tv * tv;
      }
    }
    s += __shfl_xor(s, 16);
    s += __shfl_xor(s, 32);
    q += __shfl_xor(q, 16);
    q += __shfl_xor(q, 32);
    if (quad == 0) {
      atomicAdd(&stats[f], s);
      atomicAdd(&stats[128 + f], q);
    }
  }
}

// ------- fused FFN via MFMA; BN1 coef derived per-block; z stored fp16 ------
__global__ __launch_bounds__(256) void ffn_mfma(const _Float16* __restrict__ t16,
    const float* __restrict__ stats1, const float* __restrict__ g1,
    const float* __restrict__ bb1, const _Float16* __restrict__ W1h,
    const float* __restrict__ b1, const _Float16* __restrict__ W2h,
    const float* __restrict__ b2, _Float16* __restrict__ z16,
    float* __restrict__ stats2, float invN, int N) {
  __shared__ _Float16 hs[64 * HP];  // 17.4 KB
  __shared__ _Float16 us[64 * UP];  // 33.8 KB
  __shared__ float cf[256];
  int tid = threadIdx.x;
  int base = blockIdx.x * 64;
  int lane = tid & 63, w = tid >> 6;
  int l15 = lane & 15, quad = lane >> 4;

  if (tid < 128) {
    float mu = stats1[tid] * invN;
    float var = stats1[128 + tid] * invN - mu * mu;
    float a = rsqrtf(var + 1e-5f) * g1[tid];
    cf[tid] = a;
    cf[128 + tid] = bb1[tid] - mu * a;
  }
  __syncthreads();

  for (int i = tid; i < 64 * 16; i += 256) {
    int m = i >> 4, c8 = i & 15;
    half8 tv = ((const half8*)t16)[(size_t)(base + m) * 16 + c8];
    half8 hv;
#pragma unroll
    for (int j = 0; j < 8; j++) {
      int f = c8 * 8 + j;
      hv[j] = (_Float16)((float)tv[j] * cf[f] + cf[128 + f]);
    }
    *(half8*)&hs[m * HP + c8 * 8] = hv;
  }
  __syncthreads();

  int n0 = w * 64;
  half8 afr[4][4];
#pragma unroll
  for (int mt = 0; mt < 4; mt++)
#pragma unroll
    for (int ks = 0; ks < 4; ks++)
      afr[mt][ks] = *(const half8*)&hs[(mt * 16 + l15) * HP + ks * 32 + quad * 8];

#pragma unroll
  for (int nt = 0; nt < 4; nt++) {
    int n = n0 + nt * 16 + l15;
    half8 bfr[4];
#pragma unroll
    for (int ks = 0; ks < 4; ks++)
      bfr[ks] = *(const half8*)&W1h[(size_t)n * 128 + ks * 32 + quad * 8];
    f32x4 acc[4];
#pragma unroll
    for (int mt = 0; mt < 4; mt++) acc[mt] = (f32x4){0.f, 0.f, 0.f, 0.f};
#pragma unroll
    for (int ks = 0; ks < 4; ks++)
#pragma unroll
      for (int mt = 0; mt < 4; mt++)
        acc[mt] = __builtin_amdgcn_mfma_f32_16x16x32_f16(afr[mt][ks], bfr[ks],
                                                          acc[mt], 0, 0, 0);
    float bias = b1[n];
#pragma unroll
    for (int mt = 0; mt < 4; mt++)
#pragma unroll
      for (int r = 0; r < 4; r++)
        us[(mt * 16 + quad * 4 + r) * UP + n] =
            (_Float16)fmaxf(acc[mt][r] + bias, 0.f);
  }
  __syncthreads();

  int n2 = w * 32;
  f32x4 acc2[4][2];
#pragma unroll
  for (int mt = 0; mt < 4; mt++)
#pragma unroll
    for (int nt = 0; nt < 2; nt++) acc2[mt][nt] = (f32x4){0.f, 0.f, 0.f, 0.f};
  for (int ks = 0; ks < 8; ks++) {
    half8 a[4], b[2];
#pragma unroll
    for (int mt = 0; mt < 4; mt++)
      a[mt] = *(const half8*)&us[(mt * 16 + l15) * UP + ks * 32 + quad * 8];
#pragma unroll
    for (int nt = 0; nt < 2; nt++)
      b[nt] = *(const half8*)&W2h[(size_t)(n2 + nt * 16 + l15) * 256 + ks * 32 +
                                  quad * 8];
#pragma unroll
    for (int mt = 0; mt < 4; mt++)
#pragma unroll
      for (int nt = 0; nt < 2; nt++)
        acc2[mt][nt] =
            __builtin_amdgcn_mfma_f32_16x16x32_f16(a[mt], b[nt], acc2[mt][nt], 0, 0, 0);
  }

#pragma unroll
  for (int nt = 0; nt < 2; nt++) {
    int f = n2 + nt * 16 + l15;
    float bz = b2[f];
    float s = 0.f, q = 0.f;
#pragma unroll
    for (int mt = 0; mt < 4; mt++) {
#pragma unroll
      for (int r = 0; r < 4; r++) {
        int row = mt * 16 + quad * 4 + r;
        float hv = (float)hs[row * HP + f];
        float zv = hv + acc2[mt][nt][r] + bz;
        z16[(size_t)(base + row) * DIM + f] = (_Float16)zv;
        s += zv;
        q += zv * zv;
      }
    }
    s += __shfl_xor(s, 16);
    s += __shfl_xor(s, 32);
    q += __shfl_xor(q, 16);
    q += __shfl_xor(q, 32);
    if (quad == 0) {
      atomicAdd(&stats2[f], s);
      atomicAdd(&stats2[128 + f], q);
    }
  }
}

// -------- final BN2 apply from fp16 z; coef derived per-block ----------------
__global__ __launch_bounds__(256) void final_apply(const _Float16* __restrict__ z16,
    const float* __restrict__ stats2, const float* __restrict__ g2,
    const float* __restrict__ bb2, float* __restrict__ out, float invN,
    int total8) {
  __shared__ float cf[256];
  int tid = threadIdx.x;
  if (tid < 128) {
    float mu = stats2[tid] * invN;
    float var = stats2[128 + tid] * invN - mu * mu;
    float a = rsqrtf(var + 1e-5f) * g2[tid];
    cf[tid] = a;
    cf[128 + tid] = bb2[tid] - mu * a;
  }
  __syncthreads();
  int i = blockIdx.x * 256 + tid;
  if (i >= total8) return;
  int f0 = (i * 8) & 127;
  half8 zv = ((const half8*)z16)[i];
  float4 o1, o2;
  o1.x = (float)zv[0] * cf[f0 + 0] + cf[128 + f0 + 0];
  o1.y = (float)zv[1] * cf[f0 + 1] + cf[128 + f0 + 1];
  o1.z = (float)zv[2] * cf[f0 + 2] + cf[128 + f0 + 2];
  o1.w = (float)zv[3] * cf[f0 + 3] + cf[128 + f0 + 3];
  o2.x = (float)zv[4] * cf[f0 + 4] + cf[128 + f0 + 4];
  o2.y = (float)zv[5] * cf[f0 + 5] + cf[128 + f0 + 5];
  o2.z = (float)zv[6] * cf[f0 + 6] + cf[128 + f0 + 6];
  o2.w = (float)zv[7] * cf[f0 + 7] + cf[128 + f0 + 7];
  ((float4*)out)[2 * i] = o1;
  ((float4*)out)[2 * i + 1] = o2;
}

extern "C" void kernel_launch(void* const* d_in, const int* in_sizes, int n_in,
                              void* d_out, int out_size, void* d_ws, size_t ws_size,
                              hipStream_t stream) {
  const float* x = (const float*)d_in[0];
  const int* ei = (const int*)d_in[1];
  const float* Wk = (const float*)d_in[2];
  const float* bk = (const float*)d_in[3];
  const float* Wv = (const float*)d_in[4];
  const float* bv = (const float*)d_in[5];
  const float* Wo = (const float*)d_in[6];
  const float* bo = (const float*)d_in[7];
  const float* bn1_g = (const float*)d_in[8];
  const float* bn1_b = (const float*)d_in[9];
  const float* W1 = (const float*)d_in[10];
  const float* b1 = (const float*)d_in[11];
  const float* W2 = (const float*)d_in[12];
  const float* b2 = (const float*)d_in[13];
  const float* bn2_g = (const float*)d_in[14];
  const float* bn2_b = (const float*)d_in[15];
  float* out = (float*)d_out;

  int N = in_sizes[0] / DIM;   // 40000 (= 625 * 64)
  int E = in_sizes[1] / 2;     // 640000

  // workspace layout
  unsigned char* KV8 = (unsigned char*)d_ws;              // 10.25 MB
  _Float16* attn16 = (_Float16*)(KV8 + (size_t)N * 256);  // 10.25 MB
  _Float16* t16 = attn16 + (size_t)N * DIM;               // 10.25 MB
  _Float16* z16 = t16 + (size_t)N * DIM;                  // 10.25 MB
  _Float16* W1h = z16 + (size_t)N * DIM;
  _Float16* W2h = W1h + 32768;
  _Float16* Wkh = W2h + 32768;
  _Float16* Wvh = Wkh + 16384;
  _Float16* Woh = Wvh + 16384;
  float* stats = (float*)(Woh + 16384);      // 512 floats: stats1 | stats2
  int* cnt = (int*)(stats + 512);            // N * NSHARD
  int* rs = cnt + (size_t)N * NSHARD;        // N+1
  int* rs_shard = rs + N + 1;                // N * NSHARD
  int* rank = rs_shard + (size_t)N * NSHARD; // E
  int* esrc = rank + E;                      // E
  int* bsum = esrc + E;                      // up to 256

  int nblk = (N + 255) / 256;                // 157
  int kvb = N / 64;                          // 625
  int sblk = (E + 255) / 256;                // 2500
  float invN = 1.0f / N;
  float* stats2 = stats + 256;

  conv_wall<<<512, 256, 0, stream>>>(Wk, Wv, Wo, W1, W2, Wkh, Wvh, Woh, W1h,
                                     W2h, cnt, stats, N);
  hist_rank<<<sblk, 256, 0, stream>>>(ei, cnt, rank, N, E);
  scanA<<<nblk, 256, 0, stream>>>(cnt, rs, bsum, N);
  scanBC<<<nblk, 256, 0, stream>>>(rs, bsum, cnt, rs_shard, nblk, N, E);
  scatter_kv<<<kvb + sblk, 256, 0, stream>>>(ei, rs_shard, rank, esrc, x, Wkh,
                                             bk, Wvh, bv, KV8, kvb, N, E);
  attn_agg<<<(N + 3) / 4, 256, 0, stream>>>(KV8, x, rs, esrc, attn16, N);
  o_proj_mfma<<<kvb, 256, 0, stream>>>(attn16, x, Woh, bo, t16, stats, N);
  ffn_mfma<<<kvb, 256, 0, stream>>>(t16, stats, bn1_g, bn1_b, W1h, b1, W2h, b2,
                                    z16, stats2, invN, N);
  final_apply<<<((N * DIM / 8) + 255) / 256, 256, 0, stream>>>(
      z16, stats2, bn2_g, bn2_b, out, invN, N * DIM / 8);
}